// Round 14
// baseline (234.647 us; speedup 1.0000x reference)
//
#include <hip/hip_runtime.h>

#define HID 128
#define EDGE_DIM 10
#define BN_EPS 1e-5f
#define ATT_SCALE 0.08838834764831845f  // 1/sqrt(128)

typedef unsigned short ushort_t;
typedef unsigned char uchar_t;
typedef __attribute__((ext_vector_type(8))) short short8v;
typedef __attribute__((ext_vector_type(4))) float float4v;

__device__ __forceinline__ float b2f(ushort_t u) {
    return __uint_as_float(((unsigned)u) << 16);
}
__device__ __forceinline__ ushort_t f2b(float f) {   // RNE
    unsigned u = __float_as_uint(f);
    return (ushort_t)((u + 0x7FFFu + ((u >> 16) & 1u)) >> 16);
}
__device__ __forceinline__ unsigned pack2(float a, float b) {
    return (unsigned)f2b(a) | ((unsigned)f2b(b) << 16);
}
__device__ __forceinline__ uchar_t f2fp8(float f) {   // OCP e4m3 via HW cvt
    return (uchar_t)(__builtin_amdgcn_cvt_pk_fp8_f32(f, 0.f, 0u, false) & 0xFF);
}
__device__ __forceinline__ void dec8(uint2 u, float* o) {  // 8 fp8 -> 8 f32
    auto a = __builtin_amdgcn_cvt_pk_f32_fp8(u.x, false);
    auto b = __builtin_amdgcn_cvt_pk_f32_fp8(u.x, true);
    auto c = __builtin_amdgcn_cvt_pk_f32_fp8(u.y, false);
    auto d = __builtin_amdgcn_cvt_pk_f32_fp8(u.y, true);
    o[0] = a[0]; o[1] = a[1]; o[2] = b[0]; o[3] = b[1];
    o[4] = c[0]; o[5] = c[1]; o[6] = d[0]; o[7] = d[1];
}

// ---- prep: degree+rank count, convert x/W to bf16, build MbT=(Wq^T We)^T, cvec ----
__global__ void prep_kernel(const float* __restrict__ x, const int* __restrict__ ei,
                            const float* __restrict__ Wq, const float* __restrict__ Wk,
                            const float* __restrict__ Wv, const float* __restrict__ Wskip,
                            const float* __restrict__ We, const float* __restrict__ bq,
                            ushort_t* __restrict__ xb, ushort_t* __restrict__ Wb,
                            ushort_t* __restrict__ MbT, float* __restrict__ cvec,
                            int* __restrict__ deg, int* __restrict__ rank, int N, int E) {
    int i = blockIdx.x * 256 + threadIdx.x;
    if (i < E) rank[i] = atomicAdd(&deg[ei[E + i]], 1);   // degree + stable slot id
    int xcount = N * (HID / 4);
    if (i < xcount) {
        float4 v = ((const float4*)x)[i];
        ushort4 o;
        o.x = f2b(v.x); o.y = f2b(v.y); o.z = f2b(v.z); o.w = f2b(v.w);
        ((ushort4*)xb)[i] = o;
        return;
    }
    int j = i - xcount;
    if (j < 4 * 128 * 128 / 4) {
        int w = j >> 12;
        int g = j & 4095;
        const float* W = (w == 0) ? Wq : (w == 1) ? Wk : (w == 2) ? Wv : Wskip;
        float4 v = ((const float4*)W)[g];
        ushort4 o;
        o.x = f2b(v.x); o.y = f2b(v.y); o.z = f2b(v.z); o.w = f2b(v.w);
        ((ushort4*)(Wb + (size_t)w * 128 * 128))[g] = o;
        return;
    }
    int k = j - 4 * 128 * 128 / 4;
    if (k < 16 * 128) {
        int jj = k >> 7, ii = k & 127;
        float s = 0.f;
        if (jj < EDGE_DIM) {
            for (int d = 0; d < 128; ++d)
                s += Wq[(size_t)d * 128 + ii] * We[(size_t)d * EDGE_DIM + jj];
        }
        MbT[k] = f2b(s);
        return;
    }
    int kk = k - 16 * 128;
    if (kk < 16) {
        float s = 0.f;
        if (kk < EDGE_DIM) {
            for (int d = 0; d < 128; ++d)
                s += bq[d] * We[(size_t)d * EDGE_DIM + kk];
        }
        cvec[kk] = s;
    }
}

// ---- MFMA projections: blockIdx.y = matrix; W staged once in LDS (XOR-swizzled);
// 4 waves x 2 16-node tiles per block; k/v emitted as fp8 into ONE interleaved
// record: kvp[node][c*16 + 0..7] = k dims c*8..c*8+7, +8..15 = v dims ----
__global__ __launch_bounds__(256) void mfma_proj_kernel(
    const ushort_t* __restrict__ xb, const ushort_t* __restrict__ Wb,
    const ushort_t* __restrict__ MbT, const float* __restrict__ cvec,
    const float* __restrict__ bq, const float* __restrict__ bk,
    const float* __restrict__ bv, const float* __restrict__ bskip,
    float* __restrict__ q_all, uchar_t* __restrict__ kvp,
    float* __restrict__ qwe_tbl, float* __restrict__ out, int N)
{
    const int which = blockIdx.y;         // 0=q 1=k 2=v 3=skip
    const int tid   = threadIdx.x;
    const int wid   = tid >> 6;
    const int lane  = tid & 63;
    const int nbase = blockIdx.x * 128;
    const ushort_t* W = Wb + (size_t)which * 128 * 128;
    const float* bias = (which == 0) ? bq : (which == 1) ? bk : (which == 2) ? bv : bskip;

    __shared__ ushort_t Wl[128 * 128];        // 32 KB, 16B-chunk XOR swizzle per row
    __shared__ uchar_t  tb[4][16 * 144];      // per-wave fp8 transpose buffers

    // ---- cooperative W stage: 2 threads per row, 8 chunks each ----
    {
        int row  = tid & 127;
        int half = tid >> 7;
        const ushort_t* src = W + (size_t)row * HID + half * 64;
        #pragma unroll
        for (int c = 0; c < 8; ++c) {
            int cc = half * 8 + c;
            int sw = cc ^ (row & 7);
            *(short8v*)&Wl[row * 128 + sw * 8] = *(const short8v*)&src[c * 8];
        }
    }

    const int row   = lane & 15;
    const int kgrp  = lane >> 4;
    const int col16 = lane & 15;
    const int orow  = (lane >> 4) * 4;

    float bv8[8];
    #pragma unroll
    for (int ct = 0; ct < 8; ++ct) bv8[ct] = bias[ct * 16 + col16];
    float cv = 0.f;
    short8v mreg[4];
    if (which == 0) {
        #pragma unroll
        for (int kt = 0; kt < 4; ++kt)
            mreg[kt] = *(const short8v*)&MbT[(size_t)row * HID + kt * 32 + kgrp * 8];
        if (col16 < EDGE_DIM) cv = cvec[col16];
    }

    __syncthreads();

    #pragma unroll
    for (int t = 0; t < 2; ++t) {
        const int n0 = nbase + wid * 32 + t * 16;
        if (n0 >= N) break;
        int arow = n0 + row; if (arow >= N) arow = N - 1;

        short8v a[4];
        #pragma unroll
        for (int kt = 0; kt < 4; ++kt)
            a[kt] = *(const short8v*)&xb[(size_t)arow * HID + kt * 32 + kgrp * 8];

        float4v acc[8];
        #pragma unroll
        for (int ct = 0; ct < 8; ++ct) acc[ct] = (float4v){0.f, 0.f, 0.f, 0.f};
        float4v accq = (float4v){0.f, 0.f, 0.f, 0.f};

        #pragma unroll
        for (int kt = 0; kt < 4; ++kt) {
            const int cc = kt * 4 + kgrp;
            const int sw = cc ^ (row & 7);
            #pragma unroll
            for (int ct = 0; ct < 8; ++ct) {
                short8v b = *(const short8v*)&Wl[(ct * 16 + row) * 128 + sw * 8];
                acc[ct] = __builtin_amdgcn_mfma_f32_16x16x32_bf16(a[kt], b, acc[ct], 0, 0, 0);
            }
            if (which == 0)
                accq = __builtin_amdgcn_mfma_f32_16x16x32_bf16(a[kt], mreg[kt], accq, 0, 0, 0);
        }

        // C/D layout: col = lane&15, row = (lane>>4)*4 + r
        if (which == 0 || which == 3) {
            float* dst = (which == 0) ? q_all : out;
            #pragma unroll
            for (int r = 0; r < 4; ++r) {
                int node = n0 + orow + r;
                if (node >= N) continue;
                #pragma unroll
                for (int ct = 0; ct < 8; ++ct)
                    dst[(size_t)node * HID + ct * 16 + col16] = acc[ct][r] + bv8[ct];
            }
            if (which == 0 && col16 < EDGE_DIM) {
                #pragma unroll
                for (int r = 0; r < 4; ++r) {
                    int node = n0 + orow + r;
                    if (node < N)
                        qwe_tbl[(size_t)node * EDGE_DIM + col16] = accq[r] + cv;
                }
            }
        } else {
            const int off8 = (which == 2) ? 8 : 0;     // k -> bytes 0..7, v -> 8..15
            uchar_t* tbk = tb[wid];
            #pragma unroll
            for (int r = 0; r < 4; ++r) {
                #pragma unroll
                for (int ct = 0; ct < 8; ++ct)
                    tbk[(orow + r) * 144 + ct * 16 + col16] = f2fp8(acc[ct][r] + bv8[ct]);
            }
            // wave-local transpose readback (no barrier: tb[wid] is private)
            #pragma unroll
            for (int i = lane; i < 256; i += 64) {
                int r = i >> 4, c = i & 15;
                int node = n0 + r;
                if (node < N)
                    *(uint2*)&kvp[(size_t)node * 256 + c * 16 + off8] =
                        *(const uint2*)&tbk[r * 144 + c * 8];
            }
        }
    }
}

// ---- CSR build: block-local scan, then fused partials-scan + apply ----
__global__ __launch_bounds__(256) void scan1_kernel(const int* __restrict__ deg,
                                                    int* __restrict__ rowptr,
                                                    int* __restrict__ partials, int N) {
    int i = blockIdx.x * 256 + threadIdx.x;
    int v = (i < N) ? deg[i] : 0;
    __shared__ int sm[256];
    sm[threadIdx.x] = v;
    __syncthreads();
    for (int off = 1; off < 256; off <<= 1) {
        int t = (threadIdx.x >= off) ? sm[threadIdx.x - off] : 0;
        __syncthreads();
        sm[threadIdx.x] += t;
        __syncthreads();
    }
    if (i < N) rowptr[i] = sm[threadIdx.x] - v;
    if (threadIdx.x == 255) partials[blockIdx.x] = sm[255];
}

// each block redundantly scans the <=256 partials, applies its own offset
__global__ __launch_bounds__(256) void scan23_kernel(int* __restrict__ rowptr,
                                                     const int* __restrict__ partials,
                                                     int nb, int N) {
    __shared__ int sm[256];
    int v = (threadIdx.x < nb) ? partials[threadIdx.x] : 0;
    sm[threadIdx.x] = v;
    __syncthreads();
    for (int off = 1; off < 256; off <<= 1) {
        int t = (threadIdx.x >= off) ? sm[threadIdx.x - off] : 0;
        __syncthreads();
        sm[threadIdx.x] += t;
        __syncthreads();
    }
    int boff = (blockIdx.x > 0) ? sm[blockIdx.x - 1] : 0;   // sum of partials before this block
    int i = blockIdx.x * 256 + threadIdx.x;
    if (i < N) rowptr[i] += boff;
    if (blockIdx.x == (unsigned)(nb - 1) && threadIdx.x == 0) rowptr[N] = sm[nb - 1];
}

// ---- scatter: atomic-free; also reorders ea into CSR order as bf16 ----
__global__ void scatter_kernel(const int* __restrict__ ei, const int* __restrict__ rank,
                               const int* __restrict__ rowptr, const float* __restrict__ ea,
                               int* __restrict__ csr_src, ushort_t* __restrict__ ea_csr, int E) {
    int e = blockIdx.x * 256 + threadIdx.x;
    if (e >= E) return;
    int dst = ei[E + e];
    int pos = rowptr[dst] + rank[e];
    csr_src[pos] = ei[e];
    const float* s = ea + (size_t)e * EDGE_DIM;
    float2 a = *(const float2*)s;
    float2 b = *(const float2*)(s + 2);
    float2 c = *(const float2*)(s + 4);
    float2 d = *(const float2*)(s + 6);
    float2 f = *(const float2*)(s + 8);
    unsigned* o = (unsigned*)(ea_csr + (size_t)pos * EDGE_DIM);   // 20B stride, 4B aligned
    o[0] = pack2(a.x, a.y);
    o[1] = pack2(b.x, b.y);
    o[2] = pack2(c.x, c.y);
    o[3] = pack2(d.x, d.y);
    o[4] = pack2(f.x, f.y);
}

// ---- fused attention + BN partial stats: one wave per node, 8 edges/iter,
// src prefetch, sequential p-indexed ea, interleaved fp8 k|v record;
// s = q.k + qWe.ea ; agg = (Sum ex*v + We.(Sum ex*ea)) / Sum ex ;
// then relu/relu^2 per-feature partials -> LDS -> 64-slice global atomics ----
__global__ __launch_bounds__(256) void attn_kernel(
    const ushort_t* __restrict__ ea_csr, const float* __restrict__ We,
    const float* __restrict__ q_all, const float* __restrict__ qwe_tbl,
    const uchar_t* __restrict__ kvp,
    const int* __restrict__ rowptr, const int* __restrict__ csr_src,
    float* __restrict__ out, float* __restrict__ sums_part,
    float* __restrict__ sumsq_part, int N)
{
    __shared__ float bls[128], bls2[128];
    if (threadIdx.x < 128) { bls[threadIdx.x] = 0.f; bls2[threadIdx.x] = 0.f; }
    __syncthreads();

    const int node = blockIdx.x * 4 + (threadIdx.x >> 6);
    const int lane = threadIdx.x & 63;
    const int gl = lane & 15;    // lane in 16-group; owns dims gl*8 .. gl*8+7
    const int g  = lane >> 4;    // group id
    const int d0 = gl * 8 + g * 2;

    const bool valid_node = node < N;
    int p0 = 0, p1 = 0;
    if (valid_node) { p0 = rowptr[node]; p1 = rowptr[node + 1]; }
    const bool has_edges = valid_node && (p1 > p0);

    float rx = 0.f, ry = 0.f;

    if (valid_node) {
        float2* o = (float2*)&out[(size_t)node * HID + d0];
        float2 cur = *o;      // skip projection (already there)

        if (has_edges) {
            float4 qa = *(const float4*)&q_all[(size_t)node * HID + gl * 8];
            float4 qb = *(const float4*)&q_all[(size_t)node * HID + gl * 8 + 4];
            float qsel = (gl < EDGE_DIM) ? qwe_tbl[(size_t)node * EDGE_DIM + gl] : 0.f;

            float l = 0.f, t = 0.f;
            float A[8];
            #pragma unroll
            for (int m = 0; m < 8; ++m) A[m] = 0.f;

            int pa = p0 + g, pb = pa + 4;
            bool va = pa < p1, vbv = pb < p1;
            int src_a = csr_src[va ? pa : p0];
            int src_b = csr_src[vbv ? pb : p0];

            const int iters = (p1 - p0 + 7) >> 3;
            for (int it = 0; it < iters; ++it) {
                int cpa = va ? pa : p0, cpb = vbv ? pb : p0;
                bool cva = va, cvb = vbv;
                int csa = src_a, csb = src_b;
                pa = p0 + (it + 1) * 8 + g; pb = pa + 4;         // prefetch next srcs
                va = pa < p1; vbv = pb < p1;
                src_a = csr_src[va ? pa : p0];
                src_b = csr_src[vbv ? pb : p0];

                uint4 ra = *(const uint4*)(kvp + (size_t)csa * 256 + gl * 16);
                uint4 rb = *(const uint4*)(kvp + (size_t)csb * 256 + gl * 16);
                float ea_a = (gl < EDGE_DIM) ? b2f(ea_csr[(size_t)cpa * EDGE_DIM + gl]) : 0.f;
                float ea_b = (gl < EDGE_DIM) ? b2f(ea_csr[(size_t)cpb * EDGE_DIM + gl]) : 0.f;

                float ka[8], kbf[8];
                dec8(make_uint2(ra.x, ra.y), ka);
                dec8(make_uint2(rb.x, rb.y), kbf);

                float sa = qsel * ea_a;
                sa += qa.x * ka[0] + qa.y * ka[1] + qa.z * ka[2] + qa.w * ka[3];
                sa += qb.x * ka[4] + qb.y * ka[5] + qb.z * ka[6] + qb.w * ka[7];
                float sb = qsel * ea_b;
                sb += qa.x * kbf[0] + qa.y * kbf[1] + qa.z * kbf[2] + qa.w * kbf[3];
                sb += qb.x * kbf[4] + qb.y * kbf[5] + qb.z * kbf[6] + qb.w * kbf[7];
                #pragma unroll
                for (int off = 1; off < 16; off <<= 1) {
                    sa += __shfl_xor(sa, off, 64);
                    sb += __shfl_xor(sb, off, 64);
                }
                sa = cva ? sa : -1.0e4f;
                sb = cvb ? sb : -1.0e4f;
                float exa = __expf(sa * ATT_SCALE);
                float exb = __expf(sb * ATT_SCALE);

                float vfa[8], vfb[8];
                dec8(make_uint2(ra.z, ra.w), vfa);
                dec8(make_uint2(rb.z, rb.w), vfb);

                l += exa + exb;
                t += exa * ea_a + exb * ea_b;
                #pragma unroll
                for (int m = 0; m < 8; ++m) A[m] += exa * vfa[m] + exb * vfb[m];
            }

            // cross-group reduction
            #pragma unroll
            for (int off = 16; off < 64; off <<= 1) {
                l += __shfl_xor(l, off, 64);
                t += __shfl_xor(t, off, 64);
                #pragma unroll
                for (int m = 0; m < 8; ++m) A[m] += __shfl_xor(A[m], off, 64);
            }

            // We . t : group g handles dims d0 = gl*8 + g*2, d0+1
            float tj[EDGE_DIM];
            #pragma unroll
            for (int j = 0; j < EDGE_DIM; ++j) tj[j] = __shfl(t, j, 16);

            float e0 = 0.f, e1 = 0.f;
            #pragma unroll
            for (int jj = 0; jj < 5; ++jj) {
                float2 wa = *(const float2*)&We[(size_t)d0 * EDGE_DIM + 2 * jj];
                float2 wb = *(const float2*)&We[(size_t)(d0 + 1) * EDGE_DIM + 2 * jj];
                e0 += wa.x * tj[2 * jj] + wa.y * tj[2 * jj + 1];
                e1 += wb.x * tj[2 * jj] + wb.y * tj[2 * jj + 1];
            }
            float a0 = (g == 0) ? A[0] : (g == 1) ? A[2] : (g == 2) ? A[4] : A[6];
            float a1 = (g == 0) ? A[1] : (g == 1) ? A[3] : (g == 2) ? A[5] : A[7];

            float inv = 1.f / l;
            cur.x += (a0 + e0) * inv;
            cur.y += (a1 + e1) * inv;
            *o = cur;
        }

        rx = fmaxf(cur.x, 0.f);
        ry = fmaxf(cur.y, 0.f);
    }

    // per-block BN partials (each lane owns 2 unique features; 4 waves race via atomics)
    atomicAdd(&bls[d0], rx);
    atomicAdd(&bls[d0 + 1], ry);
    atomicAdd(&bls2[d0], rx * rx);
    atomicAdd(&bls2[d0 + 1], ry * ry);
    __syncthreads();
    if (threadIdx.x < 128) {
        int sl = (blockIdx.x & 63) * 128 + threadIdx.x;
        atomicAdd(&sums_part[sl], bls[threadIdx.x]);
        atomicAdd(&sumsq_part[sl], bls2[threadIdx.x]);
    }
}

// ---- fold 64-slice BN partials into per-feature scale/shift ----
__global__ void bnscale_kernel(const float* __restrict__ sums_part,
                               const float* __restrict__ sumsq_part,
                               const float* __restrict__ gamma, const float* __restrict__ beta,
                               float* __restrict__ scale, float* __restrict__ shift, int N) {
    int f = threadIdx.x;
    if (f >= HID) return;
    float s = 0.f, s2 = 0.f;
    for (int j = 0; j < 64; ++j) {
        s  += sums_part [j * 128 + f];
        s2 += sumsq_part[j * 128 + f];
    }
    float invN = 1.f / (float)N;
    float m = s * invN;
    float var = s2 * invN - m * m;
    float sc = gamma[f] * rsqrtf(var + BN_EPS);
    scale[f] = sc;
    shift[f] = beta[f] - m * sc;
}

// ---- apply: out = relu(out)*scale + shift ----
__global__ __launch_bounds__(256) void bnapply_kernel(float* __restrict__ out,
                                                      const float* __restrict__ scale,
                                                      const float* __restrict__ shift, int N) {
    int idx = blockIdx.x * 256 + threadIdx.x;
    int total = N * (HID / 4);
    if (idx >= total) return;
    int c8 = idx & 31;
    float4 sc = ((const float4*)scale)[c8];
    float4 sh = ((const float4*)shift)[c8];
    float4 v = ((const float4*)out)[idx];
    float4 o;
    o.x = fmaxf(v.x, 0.f) * sc.x + sh.x;
    o.y = fmaxf(v.y, 0.f) * sc.y + sh.y;
    o.z = fmaxf(v.z, 0.f) * sc.z + sh.z;
    o.w = fmaxf(v.w, 0.f) * sc.w + sh.w;
    ((float4*)out)[idx] = o;
}

extern "C" void kernel_launch(void* const* d_in, const int* in_sizes, int n_in,
                              void* d_out, int out_size, void* d_ws, size_t ws_size,
                              hipStream_t stream) {
    const float* x     = (const float*)d_in[0];
    const int*   ei    = (const int*)d_in[1];
    const float* ea    = (const float*)d_in[2];
    const float* Wq    = (const float*)d_in[3];
    const float* bq    = (const float*)d_in[4];
    const float* Wk    = (const float*)d_in[5];
    const float* bk    = (const float*)d_in[6];
    const float* Wv    = (const float*)d_in[7];
    const float* bv    = (const float*)d_in[8];
    const float* We    = (const float*)d_in[9];
    const float* Wskip = (const float*)d_in[10];
    const float* bskip = (const float*)d_in[11];
    const float* gamma = (const float*)d_in[12];
    const float* beta  = (const float*)d_in[13];
    float* out = (float*)d_out;

    const int N = in_sizes[0] / HID;
    const int E = in_sizes[2] / EDGE_DIM;
    const size_t NH = (size_t)N * HID;
    const int nb = (N + 255) / 256;

    char* wsb = (char*)d_ws;
    float* q_all    = (float*)wsb;                              // NH f32
    uchar_t* kvp    = (uchar_t*)(wsb + NH * 4);                 // N*256 fp8 (interleaved k|v)
    // union region: {xb, Wb, MbT, cvec} live until proj; ea_csr lives after scatter
    char* uni       = (char*)(kvp + NH * 2);
    ushort_t* xb    = (ushort_t*)uni;                           // NH bf16
    ushort_t* Wb    = xb + NH;                                  // 4*128*128 bf16
    ushort_t* MbT   = Wb + 4 * 128 * 128;                       // 16*128 bf16
    float* cvec     = (float*)(MbT + 16 * 128);                 // 16 f32
    ushort_t* ea_csr = (ushort_t*)uni;                          // E*10 bf16 (aliases xb et al.)
    size_t uni_bytes = (size_t)E * EDGE_DIM * 2;                // 16 MB > xb-side usage
    char* tail      = uni + uni_bytes;
    float* qwe_tbl  = (float*)tail;                             // N*10 f32
    int* csr_src    = (int*)(qwe_tbl + (size_t)N * EDGE_DIM);   // E int
    int* rank       = csr_src + E;                              // E int
    int* deg        = rank + E;                                 // N (zeroed by memset)
    float* sums_part  = (float*)(deg + N);                      // 64*128 (zeroed)
    float* sumsq_part = sums_part + 64 * 128;                   // 64*128 (zeroed)
    float* scale    = sumsq_part + 64 * 128;                    // 128
    float* shift    = scale + HID;                              // 128
    int* rowptr     = (int*)(shift + HID);                      // N+1
    int* partials   = rowptr + N + 1;                           // <=256

    hipMemsetAsync(deg, 0, (size_t)(N + 2 * 64 * 128) * 4, stream);

    int ccount = N * (HID / 4) + 4 * 128 * 128 / 4 + 16 * 128 + 16;
    int pgrid = max((ccount + 255) / 256, (E + 255) / 256);
    prep_kernel<<<pgrid, 256, 0, stream>>>(x, ei, Wq, Wk, Wv, Wskip, We, bq,
                                           xb, Wb, MbT, cvec, deg, rank, N, E);

    dim3 pg((N + 127) / 128, 4);
    mfma_proj_kernel<<<pg, 256, 0, stream>>>(xb, Wb, MbT, cvec,
                                             bq, bk, bv, bskip,
                                             q_all, kvp, qwe_tbl, out, N);

    scan1_kernel<<<nb, 256, 0, stream>>>(deg, rowptr, partials, N);
    scan23_kernel<<<nb, 256, 0, stream>>>(rowptr, partials, nb, N);

    scatter_kernel<<<(E + 255) / 256, 256, 0, stream>>>(ei, rank, rowptr, ea,
                                                        csr_src, ea_csr, E);

    attn_kernel<<<(N + 3) / 4, 256, 0, stream>>>(ea_csr, We, q_all, qwe_tbl, kvp,
                                                 rowptr, csr_src, out,
                                                 sums_part, sumsq_part, N);

    bnscale_kernel<<<1, 128, 0, stream>>>(sums_part, sumsq_part, gamma, beta,
                                          scale, shift, N);
    bnapply_kernel<<<(N * (HID / 4) + 255) / 256, 256, 0, stream>>>(out, scale, shift, N);
}

// Round 15
// 204.436 us; speedup vs baseline: 1.1478x; 1.1478x over previous
//
#include <hip/hip_runtime.h>

#define HID 128
#define EDGE_DIM 10
#define BN_EPS 1e-5f
#define ATT_SCALE 0.08838834764831845f  // 1/sqrt(128)

typedef unsigned short ushort_t;
typedef unsigned char uchar_t;
typedef __attribute__((ext_vector_type(8))) short short8v;
typedef __attribute__((ext_vector_type(4))) float float4v;

__device__ __forceinline__ float b2f(ushort_t u) {
    return __uint_as_float(((unsigned)u) << 16);
}
__device__ __forceinline__ ushort_t f2b(float f) {   // RNE
    unsigned u = __float_as_uint(f);
    return (ushort_t)((u + 0x7FFFu + ((u >> 16) & 1u)) >> 16);
}
__device__ __forceinline__ unsigned pack2(float a, float b) {
    return (unsigned)f2b(a) | ((unsigned)f2b(b) << 16);
}
__device__ __forceinline__ uchar_t f2fp8(float f) {   // OCP e4m3 via HW cvt
    return (uchar_t)(__builtin_amdgcn_cvt_pk_fp8_f32(f, 0.f, 0u, false) & 0xFF);
}
__device__ __forceinline__ void dec8(uint2 u, float* o) {  // 8 fp8 -> 8 f32
    auto a = __builtin_amdgcn_cvt_pk_f32_fp8(u.x, false);
    auto b = __builtin_amdgcn_cvt_pk_f32_fp8(u.x, true);
    auto c = __builtin_amdgcn_cvt_pk_f32_fp8(u.y, false);
    auto d = __builtin_amdgcn_cvt_pk_f32_fp8(u.y, true);
    o[0] = a[0]; o[1] = a[1]; o[2] = b[0]; o[3] = b[1];
    o[4] = c[0]; o[5] = c[1]; o[6] = d[0]; o[7] = d[1];
}

// ---- prep: degree+rank count, convert x/W to bf16, build MbT=(Wq^T We)^T, cvec ----
__global__ void prep_kernel(const float* __restrict__ x, const int* __restrict__ ei,
                            const float* __restrict__ Wq, const float* __restrict__ Wk,
                            const float* __restrict__ Wv, const float* __restrict__ Wskip,
                            const float* __restrict__ We, const float* __restrict__ bq,
                            ushort_t* __restrict__ xb, ushort_t* __restrict__ Wb,
                            ushort_t* __restrict__ MbT, float* __restrict__ cvec,
                            int* __restrict__ deg, int* __restrict__ rank, int N, int E) {
    int i = blockIdx.x * 256 + threadIdx.x;
    if (i < E) rank[i] = atomicAdd(&deg[ei[E + i]], 1);   // degree + stable slot id
    int xcount = N * (HID / 4);
    if (i < xcount) {
        float4 v = ((const float4*)x)[i];
        ushort4 o;
        o.x = f2b(v.x); o.y = f2b(v.y); o.z = f2b(v.z); o.w = f2b(v.w);
        ((ushort4*)xb)[i] = o;
        return;
    }
    int j = i - xcount;
    if (j < 4 * 128 * 128 / 4) {
        int w = j >> 12;
        int g = j & 4095;
        const float* W = (w == 0) ? Wq : (w == 1) ? Wk : (w == 2) ? Wv : Wskip;
        float4 v = ((const float4*)W)[g];
        ushort4 o;
        o.x = f2b(v.x); o.y = f2b(v.y); o.z = f2b(v.z); o.w = f2b(v.w);
        ((ushort4*)(Wb + (size_t)w * 128 * 128))[g] = o;
        return;
    }
    int k = j - 4 * 128 * 128 / 4;
    if (k < 16 * 128) {
        int jj = k >> 7, ii = k & 127;
        float s = 0.f;
        if (jj < EDGE_DIM) {
            for (int d = 0; d < 128; ++d)
                s += Wq[(size_t)d * 128 + ii] * We[(size_t)d * EDGE_DIM + jj];
        }
        MbT[k] = f2b(s);
        return;
    }
    int kk = k - 16 * 128;
    if (kk < 16) {
        float s = 0.f;
        if (kk < EDGE_DIM) {
            for (int d = 0; d < 128; ++d)
                s += bq[d] * We[(size_t)d * EDGE_DIM + kk];
        }
        cvec[kk] = s;
    }
}

// ---- MFMA projections: blockIdx.y = matrix; W staged once in LDS (XOR-swizzled);
// 4 waves x 2 16-node tiles per block; k/v emitted as fp8 into ONE interleaved
// record: kvp[node][c*16 + 0..7] = k dims c*8..c*8+7, +8..15 = v dims ----
__global__ __launch_bounds__(256) void mfma_proj_kernel(
    const ushort_t* __restrict__ xb, const ushort_t* __restrict__ Wb,
    const ushort_t* __restrict__ MbT, const float* __restrict__ cvec,
    const float* __restrict__ bq, const float* __restrict__ bk,
    const float* __restrict__ bv, const float* __restrict__ bskip,
    float* __restrict__ q_all, uchar_t* __restrict__ kvp,
    float* __restrict__ qwe_tbl, float* __restrict__ out, int N)
{
    const int which = blockIdx.y;         // 0=q 1=k 2=v 3=skip
    const int tid   = threadIdx.x;
    const int wid   = tid >> 6;
    const int lane  = tid & 63;
    const int nbase = blockIdx.x * 128;
    const ushort_t* W = Wb + (size_t)which * 128 * 128;
    const float* bias = (which == 0) ? bq : (which == 1) ? bk : (which == 2) ? bv : bskip;

    __shared__ ushort_t Wl[128 * 128];        // 32 KB, 16B-chunk XOR swizzle per row
    __shared__ uchar_t  tb[4][16 * 144];      // per-wave fp8 transpose buffers

    // ---- cooperative W stage: 2 threads per row, 8 chunks each ----
    {
        int row  = tid & 127;
        int half = tid >> 7;
        const ushort_t* src = W + (size_t)row * HID + half * 64;
        #pragma unroll
        for (int c = 0; c < 8; ++c) {
            int cc = half * 8 + c;
            int sw = cc ^ (row & 7);
            *(short8v*)&Wl[row * 128 + sw * 8] = *(const short8v*)&src[c * 8];
        }
    }

    const int row   = lane & 15;
    const int kgrp  = lane >> 4;
    const int col16 = lane & 15;
    const int orow  = (lane >> 4) * 4;

    float bv8[8];
    #pragma unroll
    for (int ct = 0; ct < 8; ++ct) bv8[ct] = bias[ct * 16 + col16];
    float cv = 0.f;
    short8v mreg[4];
    if (which == 0) {
        #pragma unroll
        for (int kt = 0; kt < 4; ++kt)
            mreg[kt] = *(const short8v*)&MbT[(size_t)row * HID + kt * 32 + kgrp * 8];
        if (col16 < EDGE_DIM) cv = cvec[col16];
    }

    __syncthreads();

    #pragma unroll
    for (int t = 0; t < 2; ++t) {
        const int n0 = nbase + wid * 32 + t * 16;
        if (n0 >= N) break;
        int arow = n0 + row; if (arow >= N) arow = N - 1;

        short8v a[4];
        #pragma unroll
        for (int kt = 0; kt < 4; ++kt)
            a[kt] = *(const short8v*)&xb[(size_t)arow * HID + kt * 32 + kgrp * 8];

        float4v acc[8];
        #pragma unroll
        for (int ct = 0; ct < 8; ++ct) acc[ct] = (float4v){0.f, 0.f, 0.f, 0.f};
        float4v accq = (float4v){0.f, 0.f, 0.f, 0.f};

        #pragma unroll
        for (int kt = 0; kt < 4; ++kt) {
            const int cc = kt * 4 + kgrp;
            const int sw = cc ^ (row & 7);
            #pragma unroll
            for (int ct = 0; ct < 8; ++ct) {
                short8v b = *(const short8v*)&Wl[(ct * 16 + row) * 128 + sw * 8];
                acc[ct] = __builtin_amdgcn_mfma_f32_16x16x32_bf16(a[kt], b, acc[ct], 0, 0, 0);
            }
            if (which == 0)
                accq = __builtin_amdgcn_mfma_f32_16x16x32_bf16(a[kt], mreg[kt], accq, 0, 0, 0);
        }

        // C/D layout: col = lane&15, row = (lane>>4)*4 + r
        if (which == 0 || which == 3) {
            float* dst = (which == 0) ? q_all : out;
            #pragma unroll
            for (int r = 0; r < 4; ++r) {
                int node = n0 + orow + r;
                if (node >= N) continue;
                #pragma unroll
                for (int ct = 0; ct < 8; ++ct)
                    dst[(size_t)node * HID + ct * 16 + col16] = acc[ct][r] + bv8[ct];
            }
            if (which == 0 && col16 < EDGE_DIM) {
                #pragma unroll
                for (int r = 0; r < 4; ++r) {
                    int node = n0 + orow + r;
                    if (node < N)
                        qwe_tbl[(size_t)node * EDGE_DIM + col16] = accq[r] + cv;
                }
            }
        } else {
            const int off8 = (which == 2) ? 8 : 0;     // k -> bytes 0..7, v -> 8..15
            uchar_t* tbk = tb[wid];
            #pragma unroll
            for (int r = 0; r < 4; ++r) {
                #pragma unroll
                for (int ct = 0; ct < 8; ++ct)
                    tbk[(orow + r) * 144 + ct * 16 + col16] = f2fp8(acc[ct][r] + bv8[ct]);
            }
            // wave-local transpose readback (no barrier: tb[wid] is private)
            #pragma unroll
            for (int i = lane; i < 256; i += 64) {
                int r = i >> 4, c = i & 15;
                int node = n0 + r;
                if (node < N)
                    *(uint2*)&kvp[(size_t)node * 256 + c * 16 + off8] =
                        *(const uint2*)&tbk[r * 144 + c * 8];
            }
        }
    }
}

// ---- CSR build: block-local scan, then fused partials-scan + apply ----
__global__ __launch_bounds__(256) void scan1_kernel(const int* __restrict__ deg,
                                                    int* __restrict__ rowptr,
                                                    int* __restrict__ partials, int N) {
    int i = blockIdx.x * 256 + threadIdx.x;
    int v = (i < N) ? deg[i] : 0;
    __shared__ int sm[256];
    sm[threadIdx.x] = v;
    __syncthreads();
    for (int off = 1; off < 256; off <<= 1) {
        int t = (threadIdx.x >= off) ? sm[threadIdx.x - off] : 0;
        __syncthreads();
        sm[threadIdx.x] += t;
        __syncthreads();
    }
    if (i < N) rowptr[i] = sm[threadIdx.x] - v;
    if (threadIdx.x == 255) partials[blockIdx.x] = sm[255];
}

// each block redundantly scans the <=256 partials, applies its own offset
__global__ __launch_bounds__(256) void scan23_kernel(int* __restrict__ rowptr,
                                                     const int* __restrict__ partials,
                                                     int nb, int N) {
    __shared__ int sm[256];
    int v = (threadIdx.x < nb) ? partials[threadIdx.x] : 0;
    sm[threadIdx.x] = v;
    __syncthreads();
    for (int off = 1; off < 256; off <<= 1) {
        int t = (threadIdx.x >= off) ? sm[threadIdx.x - off] : 0;
        __syncthreads();
        sm[threadIdx.x] += t;
        __syncthreads();
    }
    int boff = (blockIdx.x > 0) ? sm[blockIdx.x - 1] : 0;   // sum of partials before this block
    int i = blockIdx.x * 256 + threadIdx.x;
    if (i < N) rowptr[i] += boff;
    if (blockIdx.x == (unsigned)(nb - 1) && threadIdx.x == 0) rowptr[N] = sm[nb - 1];
}

// ---- scatter: atomic-free; also reorders ea into CSR order as bf16 ----
__global__ void scatter_kernel(const int* __restrict__ ei, const int* __restrict__ rank,
                               const int* __restrict__ rowptr, const float* __restrict__ ea,
                               int* __restrict__ csr_src, ushort_t* __restrict__ ea_csr, int E) {
    int e = blockIdx.x * 256 + threadIdx.x;
    if (e >= E) return;
    int dst = ei[E + e];
    int pos = rowptr[dst] + rank[e];
    csr_src[pos] = ei[e];
    const float* s = ea + (size_t)e * EDGE_DIM;
    float2 a = *(const float2*)s;
    float2 b = *(const float2*)(s + 2);
    float2 c = *(const float2*)(s + 4);
    float2 d = *(const float2*)(s + 6);
    float2 f = *(const float2*)(s + 8);
    unsigned* o = (unsigned*)(ea_csr + (size_t)pos * EDGE_DIM);   // 20B stride, 4B aligned
    o[0] = pack2(a.x, a.y);
    o[1] = pack2(b.x, b.y);
    o[2] = pack2(c.x, c.y);
    o[3] = pack2(d.x, d.y);
    o[4] = pack2(f.x, f.y);
}

// ---- fused attention + BN partials: PERSISTENT grid-stride waves, one node per
// wave per loop iter; stats accumulate in registers across the loop; one LDS
// flush + one barrier per block lifetime. 8 edges/iter, src prefetch, fp8 k|v. ----
__global__ __launch_bounds__(256) void attn_kernel(
    const ushort_t* __restrict__ ea_csr, const float* __restrict__ We,
    const float* __restrict__ q_all, const float* __restrict__ qwe_tbl,
    const uchar_t* __restrict__ kvp,
    const int* __restrict__ rowptr, const int* __restrict__ csr_src,
    float* __restrict__ out, float* __restrict__ sums_part,
    float* __restrict__ sumsq_part, int N)
{
    __shared__ float bls[128], bls2[128];
    if (threadIdx.x < 128) { bls[threadIdx.x] = 0.f; bls2[threadIdx.x] = 0.f; }
    __syncthreads();

    const int wave0   = blockIdx.x * 4 + (threadIdx.x >> 6);
    const int wstride = gridDim.x * 4;
    const int lane = threadIdx.x & 63;
    const int gl = lane & 15;    // lane in 16-group; owns dims gl*8 .. gl*8+7
    const int g  = lane >> 4;    // group id
    const int d0 = gl * 8 + g * 2;

    float sx = 0.f, sy = 0.f, sx2 = 0.f, sy2 = 0.f;   // register BN partials

    for (int node = wave0; node < N; node += wstride) {
        const int p0 = rowptr[node];
        const int p1 = rowptr[node + 1];

        float2* o = (float2*)&out[(size_t)node * HID + d0];
        float2 cur = *o;                  // skip projection (already there)

        if (p1 > p0) {
            float4 qa = *(const float4*)&q_all[(size_t)node * HID + gl * 8];
            float4 qb = *(const float4*)&q_all[(size_t)node * HID + gl * 8 + 4];
            float qsel = (gl < EDGE_DIM) ? qwe_tbl[(size_t)node * EDGE_DIM + gl] : 0.f;

            float l = 0.f, t = 0.f;
            float A[8];
            #pragma unroll
            for (int m = 0; m < 8; ++m) A[m] = 0.f;

            int pa = p0 + g, pb = pa + 4;
            bool va = pa < p1, vbv = pb < p1;
            int src_a = csr_src[va ? pa : p0];
            int src_b = csr_src[vbv ? pb : p0];

            const int iters = (p1 - p0 + 7) >> 3;
            for (int it = 0; it < iters; ++it) {
                int cpa = va ? pa : p0, cpb = vbv ? pb : p0;
                bool cva = va, cvb = vbv;
                int csa = src_a, csb = src_b;
                pa = p0 + (it + 1) * 8 + g; pb = pa + 4;         // prefetch next srcs
                va = pa < p1; vbv = pb < p1;
                src_a = csr_src[va ? pa : p0];
                src_b = csr_src[vbv ? pb : p0];

                uint4 ra = *(const uint4*)(kvp + (size_t)csa * 256 + gl * 16);
                uint4 rb = *(const uint4*)(kvp + (size_t)csb * 256 + gl * 16);
                float ea_a = (gl < EDGE_DIM) ? b2f(ea_csr[(size_t)cpa * EDGE_DIM + gl]) : 0.f;
                float ea_b = (gl < EDGE_DIM) ? b2f(ea_csr[(size_t)cpb * EDGE_DIM + gl]) : 0.f;

                float ka[8], kbf[8];
                dec8(make_uint2(ra.x, ra.y), ka);
                dec8(make_uint2(rb.x, rb.y), kbf);

                float sa = qsel * ea_a;
                sa += qa.x * ka[0] + qa.y * ka[1] + qa.z * ka[2] + qa.w * ka[3];
                sa += qb.x * ka[4] + qb.y * ka[5] + qb.z * ka[6] + qb.w * ka[7];
                float sb = qsel * ea_b;
                sb += qa.x * kbf[0] + qa.y * kbf[1] + qa.z * kbf[2] + qa.w * kbf[3];
                sb += qb.x * kbf[4] + qb.y * kbf[5] + qb.z * kbf[6] + qb.w * kbf[7];
                #pragma unroll
                for (int off = 1; off < 16; off <<= 1) {
                    sa += __shfl_xor(sa, off, 64);
                    sb += __shfl_xor(sb, off, 64);
                }
                sa = cva ? sa : -1.0e4f;
                sb = cvb ? sb : -1.0e4f;
                float exa = __expf(sa * ATT_SCALE);
                float exb = __expf(sb * ATT_SCALE);

                float vfa[8], vfb[8];
                dec8(make_uint2(ra.z, ra.w), vfa);
                dec8(make_uint2(rb.z, rb.w), vfb);

                l += exa + exb;
                t += exa * ea_a + exb * ea_b;
                #pragma unroll
                for (int m = 0; m < 8; ++m) A[m] += exa * vfa[m] + exb * vfb[m];
            }

            // cross-group reduction
            #pragma unroll
            for (int off = 16; off < 64; off <<= 1) {
                l += __shfl_xor(l, off, 64);
                t += __shfl_xor(t, off, 64);
                #pragma unroll
                for (int m = 0; m < 8; ++m) A[m] += __shfl_xor(A[m], off, 64);
            }

            // We . t : group g handles dims d0, d0+1
            float tj[EDGE_DIM];
            #pragma unroll
            for (int j = 0; j < EDGE_DIM; ++j) tj[j] = __shfl(t, j, 16);

            float e0 = 0.f, e1 = 0.f;
            #pragma unroll
            for (int jj = 0; jj < 5; ++jj) {
                float2 wa = *(const float2*)&We[(size_t)d0 * EDGE_DIM + 2 * jj];
                float2 wb = *(const float2*)&We[(size_t)(d0 + 1) * EDGE_DIM + 2 * jj];
                e0 += wa.x * tj[2 * jj] + wa.y * tj[2 * jj + 1];
                e1 += wb.x * tj[2 * jj] + wb.y * tj[2 * jj + 1];
            }
            float a0 = (g == 0) ? A[0] : (g == 1) ? A[2] : (g == 2) ? A[4] : A[6];
            float a1 = (g == 0) ? A[1] : (g == 1) ? A[3] : (g == 2) ? A[5] : A[7];

            float inv = 1.f / l;
            cur.x += (a0 + e0) * inv;
            cur.y += (a1 + e1) * inv;
            *o = cur;
        }

        float rx = fmaxf(cur.x, 0.f);
        float ry = fmaxf(cur.y, 0.f);
        sx += rx;  sy += ry;
        sx2 += rx * rx;  sy2 += ry * ry;
    }

    // one LDS flush + one barrier per block lifetime
    atomicAdd(&bls[d0], sx);
    atomicAdd(&bls[d0 + 1], sy);
    atomicAdd(&bls2[d0], sx2);
    atomicAdd(&bls2[d0 + 1], sy2);
    __syncthreads();
    if (threadIdx.x < 128) {
        int sl = (blockIdx.x & 63) * 128 + threadIdx.x;
        atomicAdd(&sums_part[sl], bls[threadIdx.x]);
        atomicAdd(&sumsq_part[sl], bls2[threadIdx.x]);
    }
}

// ---- fold 64-slice BN partials into per-feature scale/shift ----
__global__ void bnscale_kernel(const float* __restrict__ sums_part,
                               const float* __restrict__ sumsq_part,
                               const float* __restrict__ gamma, const float* __restrict__ beta,
                               float* __restrict__ scale, float* __restrict__ shift, int N) {
    int f = threadIdx.x;
    if (f >= HID) return;
    float s = 0.f, s2 = 0.f;
    for (int j = 0; j < 64; ++j) {
        s  += sums_part [j * 128 + f];
        s2 += sumsq_part[j * 128 + f];
    }
    float invN = 1.f / (float)N;
    float m = s * invN;
    float var = s2 * invN - m * m;
    float sc = gamma[f] * rsqrtf(var + BN_EPS);
    scale[f] = sc;
    shift[f] = beta[f] - m * sc;
}

// ---- apply: out = relu(out)*scale + shift ----
__global__ __launch_bounds__(256) void bnapply_kernel(float* __restrict__ out,
                                                      const float* __restrict__ scale,
                                                      const float* __restrict__ shift, int N) {
    int idx = blockIdx.x * 256 + threadIdx.x;
    int total = N * (HID / 4);
    if (idx >= total) return;
    int c8 = idx & 31;
    float4 sc = ((const float4*)scale)[c8];
    float4 sh = ((const float4*)shift)[c8];
    float4 v = ((const float4*)out)[idx];
    float4 o;
    o.x = fmaxf(v.x, 0.f) * sc.x + sh.x;
    o.y = fmaxf(v.y, 0.f) * sc.y + sh.y;
    o.z = fmaxf(v.z, 0.f) * sc.z + sh.z;
    o.w = fmaxf(v.w, 0.f) * sc.w + sh.w;
    ((float4*)out)[idx] = o;
}

extern "C" void kernel_launch(void* const* d_in, const int* in_sizes, int n_in,
                              void* d_out, int out_size, void* d_ws, size_t ws_size,
                              hipStream_t stream) {
    const float* x     = (const float*)d_in[0];
    const int*   ei    = (const int*)d_in[1];
    const float* ea    = (const float*)d_in[2];
    const float* Wq    = (const float*)d_in[3];
    const float* bq    = (const float*)d_in[4];
    const float* Wk    = (const float*)d_in[5];
    const float* bk    = (const float*)d_in[6];
    const float* Wv    = (const float*)d_in[7];
    const float* bv    = (const float*)d_in[8];
    const float* We    = (const float*)d_in[9];
    const float* Wskip = (const float*)d_in[10];
    const float* bskip = (const float*)d_in[11];
    const float* gamma = (const float*)d_in[12];
    const float* beta  = (const float*)d_in[13];
    float* out = (float*)d_out;

    const int N = in_sizes[0] / HID;
    const int E = in_sizes[2] / EDGE_DIM;
    const size_t NH = (size_t)N * HID;
    const int nb = (N + 255) / 256;

    char* wsb = (char*)d_ws;
    float* q_all    = (float*)wsb;                              // NH f32
    uchar_t* kvp    = (uchar_t*)(wsb + NH * 4);                 // N*256 fp8 (interleaved k|v)
    // union region: {xb, Wb, MbT, cvec} live until proj; ea_csr lives after scatter
    char* uni       = (char*)(kvp + NH * 2);
    ushort_t* xb    = (ushort_t*)uni;                           // NH bf16
    ushort_t* Wb    = xb + NH;                                  // 4*128*128 bf16
    ushort_t* MbT   = Wb + 4 * 128 * 128;                       // 16*128 bf16
    float* cvec     = (float*)(MbT + 16 * 128);                 // 16 f32
    ushort_t* ea_csr = (ushort_t*)uni;                          // E*10 bf16 (aliases xb et al.)
    size_t uni_bytes = (size_t)E * EDGE_DIM * 2;                // 16 MB > xb-side usage
    char* tail      = uni + uni_bytes;
    float* qwe_tbl  = (float*)tail;                             // N*10 f32
    int* csr_src    = (int*)(qwe_tbl + (size_t)N * EDGE_DIM);   // E int
    int* rank       = csr_src + E;                              // E int
    int* deg        = rank + E;                                 // N (zeroed by memset)
    float* sums_part  = (float*)(deg + N);                      // 64*128 (zeroed)
    float* sumsq_part = sums_part + 64 * 128;                   // 64*128 (zeroed)
    float* scale    = sumsq_part + 64 * 128;                    // 128
    float* shift    = scale + HID;                              // 128
    int* rowptr     = (int*)(shift + HID);                      // N+1
    int* partials   = rowptr + N + 1;                           // <=256

    hipMemsetAsync(deg, 0, (size_t)(N + 2 * 64 * 128) * 4, stream);

    int ccount = N * (HID / 4) + 4 * 128 * 128 / 4 + 16 * 128 + 16;
    int pgrid = max((ccount + 255) / 256, (E + 255) / 256);
    prep_kernel<<<pgrid, 256, 0, stream>>>(x, ei, Wq, Wk, Wv, Wskip, We, bq,
                                           xb, Wb, MbT, cvec, deg, rank, N, E);

    dim3 pg((N + 127) / 128, 4);
    mfma_proj_kernel<<<pg, 256, 0, stream>>>(xb, Wb, MbT, cvec,
                                             bq, bk, bv, bskip,
                                             q_all, kvp, qwe_tbl, out, N);

    scan1_kernel<<<nb, 256, 0, stream>>>(deg, rowptr, partials, N);
    scan23_kernel<<<nb, 256, 0, stream>>>(rowptr, partials, nb, N);

    scatter_kernel<<<(E + 255) / 256, 256, 0, stream>>>(ei, rank, rowptr, ea,
                                                        csr_src, ea_csr, E);

    attn_kernel<<<2048, 256, 0, stream>>>(ea_csr, We, q_all, qwe_tbl, kvp,
                                          rowptr, csr_src, out,
                                          sums_part, sumsq_part, N);

    bnscale_kernel<<<1, 128, 0, stream>>>(sums_part, sumsq_part, gamma, beta,
                                          scale, shift, N);
    bnapply_kernel<<<(N * (HID / 4) + 255) / 256, 256, 0, stream>>>(out, scale, shift, N);
}